// Round 1
// baseline (610.673 us; speedup 1.0000x reference)
//
#include <hip/hip_runtime.h>

typedef unsigned short u16;
typedef unsigned int u32;
typedef __attribute__((ext_vector_type(8))) short bf16x8;
typedef __attribute__((ext_vector_type(4))) float f32x4;
typedef __attribute__((ext_vector_type(4))) u32 u32x4;

#define DEV __device__ __forceinline__
#define MFMA16(a, b, c) __builtin_amdgcn_mfma_f32_16x16x32_bf16(a, b, c, 0, 0, 0)

DEV u16 f2bf(float f) {
  u32 u = __float_as_uint(f);
  u32 r = (u + 0x7fffu + ((u >> 16) & 1u)) >> 16;
  return (u16)r;
}

DEV void async16(const void* g, void* l) {
  __builtin_amdgcn_global_load_lds((const __attribute__((address_space(1))) u32*)g,
                                   (__attribute__((address_space(3))) u32*)l, 16, 0, 0);
}

// ---------------- weight transpose+convert: fp32 [K,N] -> bf16 [N,K] ----------------
__global__ __launch_bounds__(256)
void wt_transpose(const float* __restrict__ w, u16* __restrict__ wt, int K, int N) {
  __shared__ float tile[32][33];
  int n0 = blockIdx.x * 32;
  int k0 = blockIdx.y * 32;
  int tx = threadIdx.x;   // 0..31
  int ty = threadIdx.y;   // 0..7
#pragma unroll
  for (int i = 0; i < 4; ++i)
    tile[ty + 8 * i][tx] = w[(size_t)(k0 + ty + 8 * i) * N + n0 + tx];
  __syncthreads();
#pragma unroll
  for (int i = 0; i < 4; ++i) {
    int n = ty + 8 * i;
    wt[(size_t)(n0 + n) * K + k0 + tx] = f2bf(tile[tx][n]);
  }
}

// ---------------- LayerNorm: fp32 row -> bf16 row ----------------
__global__ __launch_bounds__(256)
void ln_kernel(const float* __restrict__ x, const float* __restrict__ g,
               const float* __restrict__ b, u16* __restrict__ out) {
  int row = blockIdx.x;
  int tid = threadIdx.x;
  const float4* xr = (const float4*)(x + (size_t)row * 1024);
  float4 v = xr[tid];
  float s = v.x + v.y + v.z + v.w;
  float ss = v.x * v.x + v.y * v.y + v.z * v.z + v.w * v.w;
#pragma unroll
  for (int o = 32; o > 0; o >>= 1) {
    s += __shfl_down(s, o);
    ss += __shfl_down(ss, o);
  }
  __shared__ float ps[4], pss[4];
  if ((tid & 63) == 0) { ps[tid >> 6] = s; pss[tid >> 6] = ss; }
  __syncthreads();
  s = ps[0] + ps[1] + ps[2] + ps[3];
  ss = pss[0] + pss[1] + pss[2] + pss[3];
  float mu = s * (1.0f / 1024.0f);
  float var = ss * (1.0f / 1024.0f) - mu * mu;
  float rs = rsqrtf(var + 1e-5f);
  float4 gg = ((const float4*)g)[tid];
  float4 bb = ((const float4*)b)[tid];
  ushort4 ov;
  ov.x = f2bf((v.x - mu) * rs * gg.x + bb.x);
  ov.y = f2bf((v.y - mu) * rs * gg.y + bb.y);
  ov.z = f2bf((v.z - mu) * rs * gg.z + bb.z);
  ov.w = f2bf((v.w - mu) * rs * gg.w + bb.w);
  *(ushort4*)(out + (size_t)row * 1024 + tid * 4) = ov;
}

// ---------------- V transpose: bf16 [bh][2048][64] -> [bh][64][2048] ----------------
__global__ __launch_bounds__(256)
void v_transpose(const u16* __restrict__ v, u16* __restrict__ vt) {
  __shared__ u16 t[64][72];
  int s0 = blockIdx.x * 64;
  int bh = blockIdx.y;
  int tid = threadIdx.x;
  const u16* src = v + ((size_t)bh * 2048 + s0) * 64;
#pragma unroll
  for (int p = 0; p < 2; ++p) {
    int r = p * 32 + (tid >> 3);
    int c = (tid & 7) * 8;
    u32x4 a = *(const u32x4*)(src + r * 64 + c);
    const u16* pa = (const u16*)&a;
#pragma unroll
    for (int j = 0; j < 8; ++j) t[r][c + j] = pa[j];
  }
  __syncthreads();
  u16* dst = vt + (size_t)bh * 131072 + s0;
#pragma unroll
  for (int p = 0; p < 2; ++p) {
    int d = p * 32 + (tid >> 3);
    int sc = (tid & 7) * 8;
    u32x4 a;
    u16* pa = (u16*)&a;
#pragma unroll
    for (int j = 0; j < 8; ++j) pa[j] = t[sc + j][d];
    *(u32x4*)(dst + (size_t)d * 2048 + sc) = a;
  }
}

// ---------------- GEMM 128x128 tile, BK=32, 4 waves, m97-style ----------------
// A: bf16 [M,K] row-major. Bt: bf16 [N,K] row-major (i.e. B^T). All dims %128==0, K%32==0.
DEV void stage128x32(const u16* __restrict__ src, long ld, long r0, char* lds, int tid) {
  int wid = tid >> 6;
  const char* g0 = (const char*)(src + r0 * ld);
#pragma unroll
  for (int i = 0; i < 2; ++i) {
    long row = i * 64 + (tid >> 2);
    long cg = tid & 3;
    async16(g0 + (row * ld + cg * 8) * 2, lds + i * 4096 + wid * 1024);
  }
}

template <int EPI>
__global__ __launch_bounds__(256, 2)
void gemm128(const u16* __restrict__ A, const u16* __restrict__ Bt,
             const float* __restrict__ bias, int M, int N, int K,
             float* __restrict__ outf, u16* __restrict__ outb,
             const float* __restrict__ res,
             u16* __restrict__ qp, u16* __restrict__ kp, u16* __restrict__ vp) {
  __shared__ char lds[16384];
  char* ldsA = lds;
  char* ldsB = lds + 8192;
  int tid = threadIdx.x;
  int lane = tid & 63, wid = tid >> 6;
  int wr = wid >> 1, wc = wid & 1;
  long m0 = (long)blockIdx.y * 128;
  long n0 = (long)blockIdx.x * 128;

  f32x4 acc[4][4];
#pragma unroll
  for (int i = 0; i < 4; ++i)
#pragma unroll
    for (int j = 0; j < 4; ++j) acc[i][j] = (f32x4)0.0f;

  int lrow = lane & 15;
  int lkb = (lane >> 4) * 16;  // byte offset of this lane's 8-element k-chunk

  for (int k0 = 0; k0 < K; k0 += 32) {
    stage128x32(A + k0, K, m0, ldsA, tid);
    stage128x32(Bt + k0, K, n0, ldsB, tid);
    __syncthreads();
    bf16x8 af[4], bfr[4];
#pragma unroll
    for (int mi = 0; mi < 4; ++mi)
      af[mi] = *(const bf16x8*)(ldsA + (wr * 64 + mi * 16 + lrow) * 64 + lkb);
#pragma unroll
    for (int ni = 0; ni < 4; ++ni)
      bfr[ni] = *(const bf16x8*)(ldsB + (wc * 64 + ni * 16 + lrow) * 64 + lkb);
#pragma unroll
    for (int mi = 0; mi < 4; ++mi)
#pragma unroll
      for (int ni = 0; ni < 4; ++ni)
        acc[mi][ni] = MFMA16(af[mi], bfr[ni], acc[mi][ni]);
    __syncthreads();
  }

  int rgrp = (lane >> 4) * 4;
#pragma unroll
  for (int mi = 0; mi < 4; ++mi) {
#pragma unroll
    for (int ni = 0; ni < 4; ++ni) {
      long col = n0 + wc * 64 + ni * 16 + (lane & 15);
      float bv = bias[col];
#pragma unroll
      for (int r = 0; r < 4; ++r) {
        long row = m0 + wr * 64 + mi * 16 + rgrp + r;
        float c = acc[mi][ni][r] + bv;
        if (EPI == 0) {
          // QKV scatter: col in [0,3072): part=col>>10, head=(col&1023)>>6, dd=col&63
          int part = (int)(col >> 10);
          int hd = (int)(col & 1023);
          long bq = row >> 11;
          long sq = row & 2047;
          long dst = (((bq << 4) + (hd >> 6)) * 2048 + sq) * 64 + (hd & 63);
          if (part == 0) qp[dst] = f2bf(c * 0.125f);
          else if (part == 1) kp[dst] = f2bf(c);
          else vp[dst] = f2bf(c);
        } else if (EPI == 1) {
          long idx = row * (long)N + col;
          outf[idx] = c + res[idx];
        } else {
          float gl = 0.5f * c * (1.0f + erff(c * 0.70710678118f));
          outb[row * (long)N + col] = f2bf(gl);
        }
      }
    }
  }
}

// ---------------- Flash attention (causal), 4 waves x 16 q-rows, KV tile 64 ----------------
__global__ __launch_bounds__(256, 2)
void attn_kernel(const u16* __restrict__ q, const u16* __restrict__ k,
                 const u16* __restrict__ vt, u16* __restrict__ outp) {
  __shared__ char ldsK[8192];          // [64 kv][64 d] bf16
  __shared__ char ldsV[8192];          // [64 d][64 kv] bf16 (V^T tile)
  __shared__ u16 ldsP[4][1024];        // per-wave P [16][64]
  int qi = blockIdx.x;
  int bh = blockIdx.y;
  int tid = threadIdx.x, lane = tid & 63, w = tid >> 6;
  int q0 = qi * 64;
  const u16* qb = q + (size_t)bh * 131072;
  const u16* kb = k + (size_t)bh * 131072;
  const u16* vb = vt + (size_t)bh * 131072;

  int lr = lane & 15, lg = lane >> 4;
  bf16x8 qf[2];
  {
    const u16* qr = qb + (size_t)(q0 + w * 16 + lr) * 64 + lg * 8;
    qf[0] = *(const bf16x8*)(qr);
    qf[1] = *(const bf16x8*)(qr + 32);
  }

  f32x4 o[4];
#pragma unroll
  for (int i = 0; i < 4; ++i) o[i] = (f32x4)0.0f;
  float m_run[4], l_run[4];
#pragma unroll
  for (int r = 0; r < 4; ++r) { m_run[r] = -1e30f; l_run[r] = 0.0f; }

  for (int t = 0; t <= qi; ++t) {
    int kv0 = t * 64;
    {
      const char* gk = (const char*)(kb + (size_t)kv0 * 64);  // contiguous 8KB tile
#pragma unroll
      for (int i = 0; i < 2; ++i)
        async16(gk + i * 4096 + tid * 16, ldsK + i * 4096 + w * 1024);
#pragma unroll
      for (int i = 0; i < 2; ++i) {
        int vrow = i * 32 + (tid >> 3);
        int cg = tid & 7;
        async16((const char*)(vb + (size_t)vrow * 2048 + kv0 + cg * 8),
                ldsV + i * 4096 + w * 1024);
      }
    }
    __syncthreads();

    // S = Q K^T  (Q pre-scaled by 1/sqrt(d))
    f32x4 s[4];
#pragma unroll
    for (int nf = 0; nf < 4; ++nf) {
      s[nf] = (f32x4)0.0f;
#pragma unroll
      for (int ks = 0; ks < 2; ++ks) {
        bf16x8 kf = *(const bf16x8*)(ldsK + (nf * 16 + lr) * 128 + ks * 64 + lg * 16);
        s[nf] = MFMA16(qf[ks], kf, s[nf]);
      }
    }

    // causal mask
#pragma unroll
    for (int nf = 0; nf < 4; ++nf)
#pragma unroll
      for (int r = 0; r < 4; ++r) {
        int qrow = q0 + w * 16 + lg * 4 + r;
        int kvc = kv0 + nf * 16 + lr;
        if (kvc > qrow) s[nf][r] = -1e30f;
      }

    // online softmax
    float mnew[4], alpha[4], psum[4];
#pragma unroll
    for (int r = 0; r < 4; ++r) {
      float pm = fmaxf(fmaxf(s[0][r], s[1][r]), fmaxf(s[2][r], s[3][r]));
#pragma unroll
      for (int m = 1; m < 16; m <<= 1) pm = fmaxf(pm, __shfl_xor(pm, m));
      mnew[r] = fmaxf(m_run[r], pm);
      alpha[r] = __expf(m_run[r] - mnew[r]);
      psum[r] = 0.0f;
    }
#pragma unroll
    for (int nf = 0; nf < 4; ++nf)
#pragma unroll
      for (int r = 0; r < 4; ++r) {
        float p = __expf(s[nf][r] - mnew[r]);
        psum[r] += p;
        ldsP[w][(lg * 4 + r) * 64 + nf * 16 + lr] = f2bf(p);
      }
#pragma unroll
    for (int r = 0; r < 4; ++r) {
      float ps2 = psum[r];
#pragma unroll
      for (int m = 1; m < 16; m <<= 1) ps2 += __shfl_xor(ps2, m);
      l_run[r] = l_run[r] * alpha[r] + ps2;
      m_run[r] = mnew[r];
    }
#pragma unroll
    for (int nf = 0; nf < 4; ++nf)
#pragma unroll
      for (int r = 0; r < 4; ++r) o[nf][r] *= alpha[r];

    // O += P V
#pragma unroll
    for (int ks = 0; ks < 2; ++ks) {
      bf16x8 pf = *(const bf16x8*)((const char*)ldsP[w] + lr * 128 + ks * 64 + lg * 16);
#pragma unroll
      for (int nf = 0; nf < 4; ++nf) {
        bf16x8 vf = *(const bf16x8*)(ldsV + (nf * 16 + lr) * 128 + ks * 64 + lg * 16);
        o[nf] = MFMA16(pf, vf, o[nf]);
      }
    }
    __syncthreads();
  }

  int b = bh >> 4, h = bh & 15;
#pragma unroll
  for (int r = 0; r < 4; ++r) {
    int qrow = q0 + w * 16 + lg * 4 + r;
    float inv = 1.0f / l_run[r];
    size_t base = ((size_t)(b * 2048 + qrow)) * 1024 + h * 64;
#pragma unroll
    for (int nf = 0; nf < 4; ++nf)
      outp[base + nf * 16 + lr] = f2bf(o[nf][r] * inv);
  }
}

// ---------------- launch ----------------
extern "C" void kernel_launch(void* const* d_in, const int* in_sizes, int n_in,
                              void* d_out, int out_size, void* d_ws, size_t ws_size,
                              hipStream_t stream) {
  const float* x      = (const float*)d_in[0];
  const float* ln1_g  = (const float*)d_in[1];
  const float* ln1_b  = (const float*)d_in[2];
  const float* w_attn = (const float*)d_in[3];
  const float* b_attn = (const float*)d_in[4];
  const float* w_proj = (const float*)d_in[5];
  const float* b_proj = (const float*)d_in[6];
  const float* ln2_g  = (const float*)d_in[7];
  const float* ln2_b  = (const float*)d_in[8];
  const float* w_fc   = (const float*)d_in[9];
  const float* b_fc   = (const float*)d_in[10];
  const float* w_fc2  = (const float*)d_in[11];
  const float* b_fc2  = (const float*)d_in[12];
  float* out = (float*)d_out;

  char* ws = (char*)d_ws;
  u16* wt_attn = (u16*)(ws + 0);          //  6291456 B
  u16* wt_proj = (u16*)(ws + 6291456);    //  2097152 B
  u16* wt_fc   = (u16*)(ws + 8388608);    //  8388608 B
  u16* wt_fc2  = (u16*)(ws + 16777216);   //  8388608 B
  u16* xn      = (u16*)(ws + 25165824);   // 16777216 B (LN1 out, reused for LN2 out)
  float* x2    = (float*)(ws + 41943040); // 33554432 B
  char* region = ws + 75497472;           // 83886080 B union region
  u16* qb = (u16*)(region);               // 16 MiB each
  u16* kb = (u16*)(region + 16777216);
  u16* vb = (u16*)(region + 33554432);
  u16* vt = (u16*)(region + 50331648);
  u16* ao = (u16*)(region + 67108864);
  u16* hm = (u16*)(region);               // 64 MiB, overlaps dead q/k/v/vt

  dim3 tb(32, 8);
  wt_transpose<<<dim3(3072 / 32, 1024 / 32), tb, 0, stream>>>(w_attn, wt_attn, 1024, 3072);
  wt_transpose<<<dim3(1024 / 32, 1024 / 32), tb, 0, stream>>>(w_proj, wt_proj, 1024, 1024);
  wt_transpose<<<dim3(4096 / 32, 1024 / 32), tb, 0, stream>>>(w_fc, wt_fc, 1024, 4096);
  wt_transpose<<<dim3(1024 / 32, 4096 / 32), tb, 0, stream>>>(w_fc2, wt_fc2, 4096, 1024);

  ln_kernel<<<8192, 256, 0, stream>>>(x, ln1_g, ln1_b, xn);

  gemm128<0><<<dim3(3072 / 128, 8192 / 128), 256, 0, stream>>>(
      xn, wt_attn, b_attn, 8192, 3072, 1024,
      nullptr, nullptr, nullptr, qb, kb, vb);

  v_transpose<<<dim3(32, 64), 256, 0, stream>>>(vb, vt);

  attn_kernel<<<dim3(32, 64), 256, 0, stream>>>(qb, kb, vt, ao);

  gemm128<1><<<dim3(1024 / 128, 8192 / 128), 256, 0, stream>>>(
      ao, wt_proj, b_proj, 8192, 1024, 1024,
      x2, nullptr, x, nullptr, nullptr, nullptr);

  ln_kernel<<<8192, 256, 0, stream>>>(x2, ln2_g, ln2_b, xn);

  gemm128<2><<<dim3(4096 / 128, 8192 / 128), 256, 0, stream>>>(
      xn, wt_fc, b_fc, 8192, 4096, 1024,
      nullptr, hm, nullptr, nullptr, nullptr, nullptr);

  gemm128<1><<<dim3(1024 / 128, 8192 / 128), 256, 0, stream>>>(
      hm, wt_fc2, b_fc2, 8192, 1024, 4096,
      out, nullptr, x2, nullptr, nullptr, nullptr);
}

// Round 2
// 552.510 us; speedup vs baseline: 1.1053x; 1.1053x over previous
//
#include <hip/hip_runtime.h>

typedef unsigned short u16;
typedef unsigned int u32;
typedef __attribute__((ext_vector_type(8))) short bf16x8;
typedef __attribute__((ext_vector_type(4))) float f32x4;
typedef __attribute__((ext_vector_type(4))) u32 u32x4;

#define DEV __device__ __forceinline__
#define MFMA16(a, b, c) __builtin_amdgcn_mfma_f32_16x16x32_bf16(a, b, c, 0, 0, 0)

DEV u16 f2bf(float f) {
  u32 u = __float_as_uint(f);
  u32 r = (u + 0x7fffu + ((u >> 16) & 1u)) >> 16;
  return (u16)r;
}

DEV void async16(const void* g, void* l) {
  __builtin_amdgcn_global_load_lds((const __attribute__((address_space(1))) u32*)g,
                                   (__attribute__((address_space(3))) u32*)l, 16, 0, 0);
}

// ---------------- weight transpose+convert: fp32 [K,N] -> bf16 [N,K] ----------------
__global__ __launch_bounds__(256)
void wt_transpose(const float* __restrict__ w, u16* __restrict__ wt, int K, int N) {
  __shared__ float tile[32][33];
  int n0 = blockIdx.x * 32;
  int k0 = blockIdx.y * 32;
  int tx = threadIdx.x;   // 0..31
  int ty = threadIdx.y;   // 0..7
#pragma unroll
  for (int i = 0; i < 4; ++i)
    tile[ty + 8 * i][tx] = w[(size_t)(k0 + ty + 8 * i) * N + n0 + tx];
  __syncthreads();
#pragma unroll
  for (int i = 0; i < 4; ++i) {
    int n = ty + 8 * i;
    wt[(size_t)(n0 + n) * K + k0 + tx] = f2bf(tile[tx][n]);
  }
}

// ---------------- LayerNorm: fp32 row -> bf16 row ----------------
__global__ __launch_bounds__(256)
void ln_kernel(const float* __restrict__ x, const float* __restrict__ g,
               const float* __restrict__ b, u16* __restrict__ out) {
  int row = blockIdx.x;
  int tid = threadIdx.x;
  const float4* xr = (const float4*)(x + (size_t)row * 1024);
  float4 v = xr[tid];
  float s = v.x + v.y + v.z + v.w;
  float ss = v.x * v.x + v.y * v.y + v.z * v.z + v.w * v.w;
#pragma unroll
  for (int o = 32; o > 0; o >>= 1) {
    s += __shfl_down(s, o);
    ss += __shfl_down(ss, o);
  }
  __shared__ float ps[4], pss[4];
  if ((tid & 63) == 0) { ps[tid >> 6] = s; pss[tid >> 6] = ss; }
  __syncthreads();
  s = ps[0] + ps[1] + ps[2] + ps[3];
  ss = pss[0] + pss[1] + pss[2] + pss[3];
  float mu = s * (1.0f / 1024.0f);
  float var = ss * (1.0f / 1024.0f) - mu * mu;
  float rs = rsqrtf(var + 1e-5f);
  float4 gg = ((const float4*)g)[tid];
  float4 bb = ((const float4*)b)[tid];
  ushort4 ov;
  ov.x = f2bf((v.x - mu) * rs * gg.x + bb.x);
  ov.y = f2bf((v.y - mu) * rs * gg.y + bb.y);
  ov.z = f2bf((v.z - mu) * rs * gg.z + bb.z);
  ov.w = f2bf((v.w - mu) * rs * gg.w + bb.w);
  *(ushort4*)(out + (size_t)row * 1024 + tid * 4) = ov;
}

// ---------------- V transpose: bf16 [bh][2048][64] -> [bh][64][2048] ----------------
__global__ __launch_bounds__(256)
void v_transpose(const u16* __restrict__ v, u16* __restrict__ vt) {
  __shared__ u16 t[64][72];
  int s0 = blockIdx.x * 64;
  int bh = blockIdx.y;
  int tid = threadIdx.x;
  const u16* src = v + ((size_t)bh * 2048 + s0) * 64;
#pragma unroll
  for (int p = 0; p < 2; ++p) {
    int r = p * 32 + (tid >> 3);
    int c = (tid & 7) * 8;
    u32x4 a = *(const u32x4*)(src + r * 64 + c);
    const u16* pa = (const u16*)&a;
#pragma unroll
    for (int j = 0; j < 8; ++j) t[r][c + j] = pa[j];
  }
  __syncthreads();
  u16* dst = vt + (size_t)bh * 131072 + s0;
#pragma unroll
  for (int p = 0; p < 2; ++p) {
    int d = p * 32 + (tid >> 3);
    int sc = (tid & 7) * 8;
    u32x4 a;
    u16* pa = (u16*)&a;
#pragma unroll
    for (int j = 0; j < 8; ++j) pa[j] = t[sc + j][d];
    *(u32x4*)(dst + (size_t)d * 2048 + sc) = a;
  }
}

// ---------------- GEMM 128x128 tile, BK=32, 4 waves, m97-style ----------------
// A: bf16 [M,K] row-major. Bt: bf16 [N,K] row-major (i.e. B^T). All dims %128==0, K%32==0.
DEV void stage128x32(const u16* __restrict__ src, long ld, long r0, char* lds, int tid) {
  int wid = tid >> 6;
  const char* g0 = (const char*)(src + r0 * ld);
#pragma unroll
  for (int i = 0; i < 2; ++i) {
    long row = i * 64 + (tid >> 2);
    long cg = tid & 3;
    async16(g0 + (row * ld + cg * 8) * 2, lds + i * 4096 + wid * 1024);
  }
}

template <int EPI>
__global__ __launch_bounds__(256, 2)
void gemm128(const u16* __restrict__ A, const u16* __restrict__ Bt,
             const float* __restrict__ bias, int M, int N, int K,
             float* __restrict__ outf, u16* __restrict__ outb,
             const float* __restrict__ res,
             u16* __restrict__ qp, u16* __restrict__ kp, u16* __restrict__ vp) {
  __shared__ char lds[16384];
  char* ldsA = lds;
  char* ldsB = lds + 8192;
  int tid = threadIdx.x;
  int lane = tid & 63, wid = tid >> 6;
  int wr = wid >> 1, wc = wid & 1;
  long m0 = (long)blockIdx.y * 128;
  long n0 = (long)blockIdx.x * 128;

  f32x4 acc[4][4];
#pragma unroll
  for (int i = 0; i < 4; ++i)
#pragma unroll
    for (int j = 0; j < 4; ++j) acc[i][j] = (f32x4)0.0f;

  int lrow = lane & 15;
  int lkb = (lane >> 4) * 16;  // byte offset of this lane's 8-element k-chunk

  for (int k0 = 0; k0 < K; k0 += 32) {
    stage128x32(A + k0, K, m0, ldsA, tid);
    stage128x32(Bt + k0, K, n0, ldsB, tid);
    __syncthreads();
    bf16x8 af[4], bfr[4];
#pragma unroll
    for (int mi = 0; mi < 4; ++mi)
      af[mi] = *(const bf16x8*)(ldsA + (wr * 64 + mi * 16 + lrow) * 64 + lkb);
#pragma unroll
    for (int ni = 0; ni < 4; ++ni)
      bfr[ni] = *(const bf16x8*)(ldsB + (wc * 64 + ni * 16 + lrow) * 64 + lkb);
#pragma unroll
    for (int mi = 0; mi < 4; ++mi)
#pragma unroll
      for (int ni = 0; ni < 4; ++ni)
        acc[mi][ni] = MFMA16(af[mi], bfr[ni], acc[mi][ni]);
    __syncthreads();
  }

  int rgrp = (lane >> 4) * 4;
#pragma unroll
  for (int mi = 0; mi < 4; ++mi) {
#pragma unroll
    for (int ni = 0; ni < 4; ++ni) {
      long col = n0 + wc * 64 + ni * 16 + (lane & 15);
      float bv = bias[col];
#pragma unroll
      for (int r = 0; r < 4; ++r) {
        long row = m0 + wr * 64 + mi * 16 + rgrp + r;
        float c = acc[mi][ni][r] + bv;
        if (EPI == 0) {
          // QKV scatter: col in [0,3072): part=col>>10, head=(col&1023)>>6, dd=col&63
          int part = (int)(col >> 10);
          int hd = (int)(col & 1023);
          long bq = row >> 11;
          long sq = row & 2047;
          long dst = (((bq << 4) + (hd >> 6)) * 2048 + sq) * 64 + (hd & 63);
          if (part == 0) qp[dst] = f2bf(c * 0.125f);
          else if (part == 1) kp[dst] = f2bf(c);
          else vp[dst] = f2bf(c);
        } else if (EPI == 1) {
          long idx = row * (long)N + col;
          outf[idx] = c + res[idx];
        } else {
          float gl = 0.5f * c * (1.0f + erff(c * 0.70710678118f));
          outb[row * (long)N + col] = f2bf(gl);
        }
      }
    }
  }
}

// ---------------- Flash attention (causal), 4 waves x 16 q-rows, KV tile 64 ----------------
// LDS tiles XOR-swizzled: byte ^= ((row&7)<<4). K/V staged via global_load_lds with
// pre-swizzled GLOBAL source (linear LDS dest); P reg-staged with swizzled write+read.
__global__ __launch_bounds__(256, 2)
void attn_kernel(const u16* __restrict__ q, const u16* __restrict__ k,
                 const u16* __restrict__ vt, u16* __restrict__ outp) {
  __shared__ char ldsK[8192];          // [64 kv][64 d] bf16, swizzled
  __shared__ char ldsV[8192];          // [64 d][64 kv] bf16 (V^T tile), swizzled
  __shared__ char ldsP[8192];          // per-wave P [16][64] bf16, swizzled
  int qi = (int)gridDim.x - 1 - (int)blockIdx.x;  // heavy blocks first
  int bh = blockIdx.y;
  int tid = threadIdx.x, lane = tid & 63, w = tid >> 6;
  int q0 = qi * 64;
  const u16* qb = q + (size_t)bh * 131072;
  const u16* kb = k + (size_t)bh * 131072;
  const u16* vb = vt + (size_t)bh * 131072;

  int lr = lane & 15, lg = lane >> 4;
  bf16x8 qf[2];
  {
    const u16* qr = qb + (size_t)(q0 + w * 16 + lr) * 64 + lg * 8;
    qf[0] = *(const bf16x8*)(qr);
    qf[1] = *(const bf16x8*)(qr + 32);
  }

  int swz = (lr & 7) << 4;  // read-side XOR for rows lr (row&7 == lr&7)

  f32x4 o[4];
#pragma unroll
  for (int i = 0; i < 4; ++i) o[i] = (f32x4)0.0f;
  float m_run[4], l_run[4];
#pragma unroll
  for (int r = 0; r < 4; ++r) { m_run[r] = -1e30f; l_run[r] = 0.0f; }

  for (int t = 0; t <= qi; ++t) {
    int kv0 = t * 64;
    {
      // K tile: contiguous [64][64] bf16 in global; source pre-swizzled so that
      // LDS[off] = K_tile[off ^ ((row&7)<<4)] (XOR touches bits 4-6 only -> involution).
      const char* gk = (const char*)(kb + (size_t)kv0 * 64);
#pragma unroll
      for (int i = 0; i < 2; ++i) {
        int off = i * 4096 + tid * 16;
        int src = off ^ (((off >> 7) & 7) << 4);
        async16(gk + src, ldsK + i * 4096 + w * 1024);
      }
      // V^T tile: rows d (stride 2048 elems in global), cols kv; same swizzle.
#pragma unroll
      for (int i = 0; i < 2; ++i) {
        int vrow = i * 32 + (tid >> 3);
        int cb = ((tid & 7) * 16) ^ ((vrow & 7) << 4);
        async16((const char*)vb + (size_t)vrow * 4096 + (size_t)kv0 * 2 + cb,
                ldsV + i * 4096 + w * 1024);
      }
    }
    __syncthreads();

    // S = Q K^T  (Q pre-scaled by 1/sqrt(d))
    f32x4 s[4];
#pragma unroll
    for (int nf = 0; nf < 4; ++nf) {
      s[nf] = (f32x4)0.0f;
#pragma unroll
      for (int ks = 0; ks < 2; ++ks) {
        bf16x8 kf = *(const bf16x8*)(ldsK + (nf * 16 + lr) * 128 +
                                     ((ks * 64 + lg * 16) ^ swz));
        s[nf] = MFMA16(qf[ks], kf, s[nf]);
      }
    }

    // causal mask
#pragma unroll
    for (int nf = 0; nf < 4; ++nf)
#pragma unroll
      for (int r = 0; r < 4; ++r) {
        int qrow = q0 + w * 16 + lg * 4 + r;
        int kvc = kv0 + nf * 16 + lr;
        if (kvc > qrow) s[nf][r] = -1e30f;
      }

    // online softmax
    float mnew[4], alpha[4], psum[4];
#pragma unroll
    for (int r = 0; r < 4; ++r) {
      float pm = fmaxf(fmaxf(s[0][r], s[1][r]), fmaxf(s[2][r], s[3][r]));
#pragma unroll
      for (int m = 1; m < 16; m <<= 1) pm = fmaxf(pm, __shfl_xor(pm, m));
      mnew[r] = fmaxf(m_run[r], pm);
      alpha[r] = __expf(m_run[r] - mnew[r]);
      psum[r] = 0.0f;
    }
#pragma unroll
    for (int nf = 0; nf < 4; ++nf)
#pragma unroll
      for (int r = 0; r < 4; ++r) {
        float p = __expf(s[nf][r] - mnew[r]);
        psum[r] += p;
        int prow = lg * 4 + r;
        int pb = ((nf * 16 + lr) * 2) ^ ((prow & 7) << 4);
        *(u16*)(ldsP + w * 2048 + prow * 128 + pb) = f2bf(p);
      }
#pragma unroll
    for (int r = 0; r < 4; ++r) {
      float ps2 = psum[r];
#pragma unroll
      for (int m = 1; m < 16; m <<= 1) ps2 += __shfl_xor(ps2, m);
      l_run[r] = l_run[r] * alpha[r] + ps2;
      m_run[r] = mnew[r];
    }
#pragma unroll
    for (int nf = 0; nf < 4; ++nf)
#pragma unroll
      for (int r = 0; r < 4; ++r) o[nf][r] *= alpha[r];

    // O += P V
#pragma unroll
    for (int ks = 0; ks < 2; ++ks) {
      bf16x8 pf = *(const bf16x8*)(ldsP + w * 2048 + lr * 128 +
                                   ((ks * 64 + lg * 16) ^ swz));
#pragma unroll
      for (int nf = 0; nf < 4; ++nf) {
        bf16x8 vf = *(const bf16x8*)(ldsV + (nf * 16 + lr) * 128 +
                                     ((ks * 64 + lg * 16) ^ swz));
        o[nf] = MFMA16(pf, vf, o[nf]);
      }
    }
    __syncthreads();
  }

  int b = bh >> 4, h = bh & 15;
#pragma unroll
  for (int r = 0; r < 4; ++r) {
    int qrow = q0 + w * 16 + lg * 4 + r;
    float inv = 1.0f / l_run[r];
    size_t base = ((size_t)(b * 2048 + qrow)) * 1024 + h * 64;
#pragma unroll
    for (int nf = 0; nf < 4; ++nf)
      outp[base + nf * 16 + lr] = f2bf(o[nf][r] * inv);
  }
}

// ---------------- launch ----------------
extern "C" void kernel_launch(void* const* d_in, const int* in_sizes, int n_in,
                              void* d_out, int out_size, void* d_ws, size_t ws_size,
                              hipStream_t stream) {
  const float* x      = (const float*)d_in[0];
  const float* ln1_g  = (const float*)d_in[1];
  const float* ln1_b  = (const float*)d_in[2];
  const float* w_attn = (const float*)d_in[3];
  const float* b_attn = (const float*)d_in[4];
  const float* w_proj = (const float*)d_in[5];
  const float* b_proj = (const float*)d_in[6];
  const float* ln2_g  = (const float*)d_in[7];
  const float* ln2_b  = (const float*)d_in[8];
  const float* w_fc   = (const float*)d_in[9];
  const float* b_fc   = (const float*)d_in[10];
  const float* w_fc2  = (const float*)d_in[11];
  const float* b_fc2  = (const float*)d_in[12];
  float* out = (float*)d_out;

  char* ws = (char*)d_ws;
  u16* wt_attn = (u16*)(ws + 0);          //  6291456 B
  u16* wt_proj = (u16*)(ws + 6291456);    //  2097152 B
  u16* wt_fc   = (u16*)(ws + 8388608);    //  8388608 B
  u16* wt_fc2  = (u16*)(ws + 16777216);   //  8388608 B
  u16* xn      = (u16*)(ws + 25165824);   // 16777216 B (LN1 out, reused for LN2 out)
  float* x2    = (float*)(ws + 41943040); // 33554432 B
  char* region = ws + 75497472;           // 83886080 B union region
  u16* qb = (u16*)(region);               // 16 MiB each
  u16* kb = (u16*)(region + 16777216);
  u16* vb = (u16*)(region + 33554432);
  u16* vt = (u16*)(region + 50331648);
  u16* ao = (u16*)(region + 67108864);
  u16* hm = (u16*)(region);               // 64 MiB, overlaps dead q/k/v/vt

  dim3 tb(32, 8);
  wt_transpose<<<dim3(3072 / 32, 1024 / 32), tb, 0, stream>>>(w_attn, wt_attn, 1024, 3072);
  wt_transpose<<<dim3(1024 / 32, 1024 / 32), tb, 0, stream>>>(w_proj, wt_proj, 1024, 1024);
  wt_transpose<<<dim3(4096 / 32, 1024 / 32), tb, 0, stream>>>(w_fc, wt_fc, 1024, 4096);
  wt_transpose<<<dim3(1024 / 32, 4096 / 32), tb, 0, stream>>>(w_fc2, wt_fc2, 4096, 1024);

  ln_kernel<<<8192, 256, 0, stream>>>(x, ln1_g, ln1_b, xn);

  gemm128<0><<<dim3(3072 / 128, 8192 / 128), 256, 0, stream>>>(
      xn, wt_attn, b_attn, 8192, 3072, 1024,
      nullptr, nullptr, nullptr, qb, kb, vb);

  v_transpose<<<dim3(32, 64), 256, 0, stream>>>(vb, vt);

  attn_kernel<<<dim3(32, 64), 256, 0, stream>>>(qb, kb, vt, ao);

  gemm128<1><<<dim3(1024 / 128, 8192 / 128), 256, 0, stream>>>(
      ao, wt_proj, b_proj, 8192, 1024, 1024,
      x2, nullptr, x, nullptr, nullptr, nullptr);

  ln_kernel<<<8192, 256, 0, stream>>>(x2, ln2_g, ln2_b, xn);

  gemm128<2><<<dim3(4096 / 128, 8192 / 128), 256, 0, stream>>>(
      xn, wt_fc, b_fc, 8192, 4096, 1024,
      nullptr, hm, nullptr, nullptr, nullptr, nullptr);

  gemm128<1><<<dim3(1024 / 128, 8192 / 128), 256, 0, stream>>>(
      hm, wt_fc2, b_fc2, 8192, 1024, 4096,
      out, nullptr, x2, nullptr, nullptr, nullptr);
}

// Round 3
// 536.748 us; speedup vs baseline: 1.1377x; 1.0294x over previous
//
#include <hip/hip_runtime.h>

typedef unsigned short u16;
typedef unsigned int u32;
typedef __attribute__((ext_vector_type(8))) short bf16x8;
typedef __attribute__((ext_vector_type(4))) float f32x4;
typedef __attribute__((ext_vector_type(4))) u32 u32x4;

#define DEV __device__ __forceinline__
#define MFMA16(a, b, c) __builtin_amdgcn_mfma_f32_16x16x32_bf16(a, b, c, 0, 0, 0)

DEV u16 f2bf(float f) {
  u32 u = __float_as_uint(f);
  u32 r = (u + 0x7fffu + ((u >> 16) & 1u)) >> 16;
  return (u16)r;
}

DEV void async16(const void* g, void* l) {
  __builtin_amdgcn_global_load_lds((const __attribute__((address_space(1))) u32*)g,
                                   (__attribute__((address_space(3))) u32*)l, 16, 0, 0);
}

// ---------------- weight transpose+convert: fp32 [K,N] -> bf16 [N,K] ----------------
__global__ __launch_bounds__(256)
void wt_transpose(const float* __restrict__ w, u16* __restrict__ wt, int K, int N) {
  __shared__ float tile[32][33];
  int n0 = blockIdx.x * 32;
  int k0 = blockIdx.y * 32;
  int tx = threadIdx.x;   // 0..31
  int ty = threadIdx.y;   // 0..7
#pragma unroll
  for (int i = 0; i < 4; ++i)
    tile[ty + 8 * i][tx] = w[(size_t)(k0 + ty + 8 * i) * N + n0 + tx];
  __syncthreads();
#pragma unroll
  for (int i = 0; i < 4; ++i) {
    int n = ty + 8 * i;
    wt[(size_t)(n0 + n) * K + k0 + tx] = f2bf(tile[tx][n]);
  }
}

// ---------------- LayerNorm: fp32 row -> bf16 row ----------------
__global__ __launch_bounds__(256)
void ln_kernel(const float* __restrict__ x, const float* __restrict__ g,
               const float* __restrict__ b, u16* __restrict__ out) {
  int row = blockIdx.x;
  int tid = threadIdx.x;
  const float4* xr = (const float4*)(x + (size_t)row * 1024);
  float4 v = xr[tid];
  float s = v.x + v.y + v.z + v.w;
  float ss = v.x * v.x + v.y * v.y + v.z * v.z + v.w * v.w;
#pragma unroll
  for (int o = 32; o > 0; o >>= 1) {
    s += __shfl_down(s, o);
    ss += __shfl_down(ss, o);
  }
  __shared__ float ps[4], pss[4];
  if ((tid & 63) == 0) { ps[tid >> 6] = s; pss[tid >> 6] = ss; }
  __syncthreads();
  s = ps[0] + ps[1] + ps[2] + ps[3];
  ss = pss[0] + pss[1] + pss[2] + pss[3];
  float mu = s * (1.0f / 1024.0f);
  float var = ss * (1.0f / 1024.0f) - mu * mu;
  float rs = rsqrtf(var + 1e-5f);
  float4 gg = ((const float4*)g)[tid];
  float4 bb = ((const float4*)b)[tid];
  ushort4 ov;
  ov.x = f2bf((v.x - mu) * rs * gg.x + bb.x);
  ov.y = f2bf((v.y - mu) * rs * gg.y + bb.y);
  ov.z = f2bf((v.z - mu) * rs * gg.z + bb.z);
  ov.w = f2bf((v.w - mu) * rs * gg.w + bb.w);
  *(ushort4*)(out + (size_t)row * 1024 + tid * 4) = ov;
}

// ---------------- V transpose: bf16 [bh][2048][64] -> [bh][64][2048] ----------------
__global__ __launch_bounds__(256)
void v_transpose(const u16* __restrict__ v, u16* __restrict__ vt) {
  __shared__ u16 t[64][72];
  int s0 = blockIdx.x * 64;
  int bh = blockIdx.y;
  int tid = threadIdx.x;
  const u16* src = v + ((size_t)bh * 2048 + s0) * 64;
#pragma unroll
  for (int p = 0; p < 2; ++p) {
    int r = p * 32 + (tid >> 3);
    int c = (tid & 7) * 8;
    u32x4 a = *(const u32x4*)(src + r * 64 + c);
    const u16* pa = (const u16*)&a;
#pragma unroll
    for (int j = 0; j < 8; ++j) t[r][c + j] = pa[j];
  }
  __syncthreads();
  u16* dst = vt + (size_t)bh * 131072 + s0;
#pragma unroll
  for (int p = 0; p < 2; ++p) {
    int d = p * 32 + (tid >> 3);
    int sc = (tid & 7) * 8;
    u32x4 a;
    u16* pa = (u16*)&a;
#pragma unroll
    for (int j = 0; j < 8; ++j) pa[j] = t[sc + j][d];
    *(u32x4*)(dst + (size_t)d * 2048 + sc) = a;
  }
}

// ---------------- GEMM 128x128 tile, BK=32, 4 waves, m97-style ----------------
// A: bf16 [M,K] row-major. Bt: bf16 [N,K] row-major (i.e. B^T). All dims %128==0, K%32==0.
DEV void stage128x32(const u16* __restrict__ src, long ld, long r0, char* lds, int tid) {
  int wid = tid >> 6;
  const char* g0 = (const char*)(src + r0 * ld);
#pragma unroll
  for (int i = 0; i < 2; ++i) {
    long row = i * 64 + (tid >> 2);
    long cg = tid & 3;
    async16(g0 + (row * ld + cg * 8) * 2, lds + i * 4096 + wid * 1024);
  }
}

template <int EPI>
__global__ __launch_bounds__(256, 2)
void gemm128(const u16* __restrict__ A, const u16* __restrict__ Bt,
             const float* __restrict__ bias, int M, int N, int K,
             float* __restrict__ outf, u16* __restrict__ outb,
             const float* __restrict__ res,
             u16* __restrict__ qp, u16* __restrict__ kp, u16* __restrict__ vp) {
  __shared__ char lds[16384];
  char* ldsA = lds;
  char* ldsB = lds + 8192;
  int tid = threadIdx.x;
  int lane = tid & 63, wid = tid >> 6;
  int wr = wid >> 1, wc = wid & 1;
  long m0 = (long)blockIdx.y * 128;
  long n0 = (long)blockIdx.x * 128;

  f32x4 acc[4][4];
#pragma unroll
  for (int i = 0; i < 4; ++i)
#pragma unroll
    for (int j = 0; j < 4; ++j) acc[i][j] = (f32x4)0.0f;

  int lrow = lane & 15;
  int lkb = (lane >> 4) * 16;  // byte offset of this lane's 8-element k-chunk

  for (int k0 = 0; k0 < K; k0 += 32) {
    stage128x32(A + k0, K, m0, ldsA, tid);
    stage128x32(Bt + k0, K, n0, ldsB, tid);
    __syncthreads();
    bf16x8 af[4], bfr[4];
#pragma unroll
    for (int mi = 0; mi < 4; ++mi)
      af[mi] = *(const bf16x8*)(ldsA + (wr * 64 + mi * 16 + lrow) * 64 + lkb);
#pragma unroll
    for (int ni = 0; ni < 4; ++ni)
      bfr[ni] = *(const bf16x8*)(ldsB + (wc * 64 + ni * 16 + lrow) * 64 + lkb);
#pragma unroll
    for (int mi = 0; mi < 4; ++mi)
#pragma unroll
      for (int ni = 0; ni < 4; ++ni)
        acc[mi][ni] = MFMA16(af[mi], bfr[ni], acc[mi][ni]);
    __syncthreads();
  }

  int rgrp = (lane >> 4) * 4;
#pragma unroll
  for (int mi = 0; mi < 4; ++mi) {
#pragma unroll
    for (int ni = 0; ni < 4; ++ni) {
      long col = n0 + wc * 64 + ni * 16 + (lane & 15);
      float bv = bias[col];
#pragma unroll
      for (int r = 0; r < 4; ++r) {
        long row = m0 + wr * 64 + mi * 16 + rgrp + r;
        float c = acc[mi][ni][r] + bv;
        if (EPI == 0) {
          // QKV scatter: col in [0,3072): part=col>>10, head=(col&1023)>>6, dd=col&63
          int part = (int)(col >> 10);
          int hd = (int)(col & 1023);
          long bq = row >> 11;
          long sq = row & 2047;
          long dst = (((bq << 4) + (hd >> 6)) * 2048 + sq) * 64 + (hd & 63);
          if (part == 0) qp[dst] = f2bf(c * 0.125f);
          else if (part == 1) kp[dst] = f2bf(c);
          else vp[dst] = f2bf(c);
        } else if (EPI == 1) {
          long idx = row * (long)N + col;
          outf[idx] = c + res[idx];
        } else {
          float gl = 0.5f * c * (1.0f + erff(c * 0.70710678118f));
          outb[row * (long)N + col] = f2bf(gl);
        }
      }
    }
  }
}

// ---------------- Flash attention (causal), QBLK=128 (4 waves x 32 q-rows), KV tile 64,
// double-buffered K/V staging (issue-early prefetch), XOR-swizzled LDS ----------------
__global__ __launch_bounds__(256, 2)
void attn_kernel(const u16* __restrict__ q, const u16* __restrict__ k,
                 const u16* __restrict__ vt, u16* __restrict__ outp) {
  __shared__ char ldsK[2][8192];   // [64 kv][64 d] bf16, swizzled, double-buffered
  __shared__ char ldsV[2][8192];   // [64 d][64 kv] bf16 (V^T tile), swizzled, dbuf
  __shared__ char ldsP[4][4096];   // per-wave P [32][64] bf16, swizzled
  int qi = (int)gridDim.x - 1 - (int)blockIdx.x;  // heavy blocks first
  int bh = blockIdx.y;
  int tid = threadIdx.x, lane = tid & 63, w = tid >> 6;
  int q0 = qi * 128;
  const u16* qb = q + (size_t)bh * 131072;
  const u16* kb = k + (size_t)bh * 131072;
  const u16* vb = vt + (size_t)bh * 131072;

  int lr = lane & 15, lg = lane >> 4;
  int swz = (lr & 7) << 4;  // read-side XOR (row & 7 == lr & 7 for all fragment rows)

  bf16x8 qf[2][2];
#pragma unroll
  for (int fq = 0; fq < 2; ++fq) {
    const u16* qr = qb + (size_t)(q0 + w * 32 + fq * 16 + lr) * 64 + lg * 8;
    qf[fq][0] = *(const bf16x8*)(qr);
    qf[fq][1] = *(const bf16x8*)(qr + 32);
  }

  f32x4 o[2][4];
#pragma unroll
  for (int fq = 0; fq < 2; ++fq)
#pragma unroll
    for (int i = 0; i < 4; ++i) o[fq][i] = (f32x4)0.0f;
  float m_run[2][4], l_run[2][4];
#pragma unroll
  for (int fq = 0; fq < 2; ++fq)
#pragma unroll
    for (int r = 0; r < 4; ++r) { m_run[fq][r] = -1e30f; l_run[fq][r] = 0.0f; }

  int nt = 2 * qi + 2;

  auto stage = [&](int buf, int t) {
    int kv0 = t * 64;
    // K tile: contiguous [64][64] bf16; source pre-swizzled (XOR bits 4-6 within row).
    const char* gk = (const char*)(kb + (size_t)kv0 * 64);
#pragma unroll
    for (int i = 0; i < 2; ++i) {
      int off = i * 4096 + tid * 16;
      int src = off ^ (((off >> 7) & 7) << 4);
      async16(gk + src, &ldsK[buf][i * 4096 + w * 1024]);
    }
    // V^T tile: rows d (global stride 4096B), cols kv; same swizzle.
#pragma unroll
    for (int i = 0; i < 2; ++i) {
      int vrow = i * 32 + (tid >> 3);
      int cb = ((tid & 7) * 16) ^ ((vrow & 7) << 4);
      async16((const char*)vb + (size_t)vrow * 4096 + (size_t)kv0 * 2 + cb,
              &ldsV[buf][i * 4096 + w * 1024]);
    }
  };

  stage(0, 0);
  __syncthreads();  // drain prologue loads
  int cur = 0;

  for (int t = 0; t < nt; ++t) {
    if (t + 1 < nt) stage(cur ^ 1, t + 1);  // issue next-tile loads EARLY
    int kv0 = t * 64;

    // S = Q K^T  (Q pre-scaled by 1/sqrt(d))
    f32x4 s[2][4];
    __builtin_amdgcn_s_setprio(1);
#pragma unroll
    for (int nf = 0; nf < 4; ++nf) {
#pragma unroll
      for (int fq = 0; fq < 2; ++fq) s[fq][nf] = (f32x4)0.0f;
#pragma unroll
      for (int ks = 0; ks < 2; ++ks) {
        bf16x8 kf = *(const bf16x8*)(&ldsK[cur][(nf * 16 + lr) * 128 +
                                               ((ks * 64 + lg * 16) ^ swz)]);
#pragma unroll
        for (int fq = 0; fq < 2; ++fq)
          s[fq][nf] = MFMA16(qf[fq][ks], kf, s[fq][nf]);
      }
    }
    __builtin_amdgcn_s_setprio(0);

    // causal mask — only the last two tiles can touch the diagonal
    if (t + 2 >= nt) {
#pragma unroll
      for (int fq = 0; fq < 2; ++fq)
#pragma unroll
        for (int nf = 0; nf < 4; ++nf)
#pragma unroll
          for (int r = 0; r < 4; ++r) {
            int qrow = q0 + w * 32 + fq * 16 + lg * 4 + r;
            int kvc = kv0 + nf * 16 + lr;
            if (kvc > qrow) s[fq][nf][r] = -1e30f;
          }
    }

    // online softmax
    float mnew[2][4], alpha[2][4], psum[2][4];
#pragma unroll
    for (int fq = 0; fq < 2; ++fq)
#pragma unroll
      for (int r = 0; r < 4; ++r) {
        float pm = fmaxf(fmaxf(s[fq][0][r], s[fq][1][r]),
                         fmaxf(s[fq][2][r], s[fq][3][r]));
#pragma unroll
        for (int m = 1; m < 16; m <<= 1) pm = fmaxf(pm, __shfl_xor(pm, m));
        mnew[fq][r] = fmaxf(m_run[fq][r], pm);
        alpha[fq][r] = __expf(m_run[fq][r] - mnew[fq][r]);
        m_run[fq][r] = mnew[fq][r];
        psum[fq][r] = 0.0f;
      }
#pragma unroll
    for (int fq = 0; fq < 2; ++fq)
#pragma unroll
      for (int nf = 0; nf < 4; ++nf)
#pragma unroll
        for (int r = 0; r < 4; ++r) {
          float p = __expf(s[fq][nf][r] - mnew[fq][r]);
          psum[fq][r] += p;
          int prow = fq * 16 + lg * 4 + r;
          int pb = ((nf * 16 + lr) * 2) ^ ((prow & 7) << 4);
          *(u16*)(&ldsP[w][prow * 128 + pb]) = f2bf(p);
        }
#pragma unroll
    for (int fq = 0; fq < 2; ++fq)
#pragma unroll
      for (int r = 0; r < 4; ++r) {
        float ps2 = psum[fq][r];
#pragma unroll
        for (int m = 1; m < 16; m <<= 1) ps2 += __shfl_xor(ps2, m);
        l_run[fq][r] = l_run[fq][r] * alpha[fq][r] + ps2;
      }
#pragma unroll
    for (int fq = 0; fq < 2; ++fq)
#pragma unroll
      for (int nf = 0; nf < 4; ++nf)
#pragma unroll
        for (int r = 0; r < 4; ++r) o[fq][nf][r] *= alpha[fq][r];

    // O += P V   (P per-wave in LDS; wave-local DS ops are in-order)
    __builtin_amdgcn_s_setprio(1);
#pragma unroll
    for (int ks = 0; ks < 2; ++ks) {
      bf16x8 pf[2];
#pragma unroll
      for (int fq = 0; fq < 2; ++fq)
        pf[fq] = *(const bf16x8*)(&ldsP[w][(fq * 16 + lr) * 128 +
                                           ((ks * 64 + lg * 16) ^ swz)]);
#pragma unroll
      for (int nf = 0; nf < 4; ++nf) {
        bf16x8 vf = *(const bf16x8*)(&ldsV[cur][(nf * 16 + lr) * 128 +
                                               ((ks * 64 + lg * 16) ^ swz)]);
#pragma unroll
        for (int fq = 0; fq < 2; ++fq)
          o[fq][nf] = MFMA16(pf[fq], vf, o[fq][nf]);
      }
    }
    __builtin_amdgcn_s_setprio(0);

    __syncthreads();  // drains prefetch vmcnt + syncs buffer swap
    cur ^= 1;
  }

  int b = bh >> 4, h = bh & 15;
#pragma unroll
  for (int fq = 0; fq < 2; ++fq)
#pragma unroll
    for (int r = 0; r < 4; ++r) {
      int qrow = q0 + w * 32 + fq * 16 + lg * 4 + r;
      float inv = 1.0f / l_run[fq][r];
      size_t base = ((size_t)(b * 2048 + qrow)) * 1024 + h * 64;
#pragma unroll
      for (int nf = 0; nf < 4; ++nf)
        outp[base + nf * 16 + lr] = f2bf(o[fq][nf][r] * inv);
    }
}

// ---------------- launch ----------------
extern "C" void kernel_launch(void* const* d_in, const int* in_sizes, int n_in,
                              void* d_out, int out_size, void* d_ws, size_t ws_size,
                              hipStream_t stream) {
  const float* x      = (const float*)d_in[0];
  const float* ln1_g  = (const float*)d_in[1];
  const float* ln1_b  = (const float*)d_in[2];
  const float* w_attn = (const float*)d_in[3];
  const float* b_attn = (const float*)d_in[4];
  const float* w_proj = (const float*)d_in[5];
  const float* b_proj = (const float*)d_in[6];
  const float* ln2_g  = (const float*)d_in[7];
  const float* ln2_b  = (const float*)d_in[8];
  const float* w_fc   = (const float*)d_in[9];
  const float* b_fc   = (const float*)d_in[10];
  const float* w_fc2  = (const float*)d_in[11];
  const float* b_fc2  = (const float*)d_in[12];
  float* out = (float*)d_out;

  char* ws = (char*)d_ws;
  u16* wt_attn = (u16*)(ws + 0);          //  6291456 B
  u16* wt_proj = (u16*)(ws + 6291456);    //  2097152 B
  u16* wt_fc   = (u16*)(ws + 8388608);    //  8388608 B
  u16* wt_fc2  = (u16*)(ws + 16777216);   //  8388608 B
  u16* xn      = (u16*)(ws + 25165824);   // 16777216 B (LN1 out, reused for LN2 out)
  float* x2    = (float*)(ws + 41943040); // 33554432 B
  char* region = ws + 75497472;           // 83886080 B union region
  u16* qb = (u16*)(region);               // 16 MiB each
  u16* kb = (u16*)(region + 16777216);
  u16* vb = (u16*)(region + 33554432);
  u16* vt = (u16*)(region + 50331648);
  u16* ao = (u16*)(region + 67108864);
  u16* hm = (u16*)(region);               // 64 MiB, overlaps dead q/k/v/vt

  dim3 tb(32, 8);
  wt_transpose<<<dim3(3072 / 32, 1024 / 32), tb, 0, stream>>>(w_attn, wt_attn, 1024, 3072);
  wt_transpose<<<dim3(1024 / 32, 1024 / 32), tb, 0, stream>>>(w_proj, wt_proj, 1024, 1024);
  wt_transpose<<<dim3(4096 / 32, 1024 / 32), tb, 0, stream>>>(w_fc, wt_fc, 1024, 4096);
  wt_transpose<<<dim3(1024 / 32, 4096 / 32), tb, 0, stream>>>(w_fc2, wt_fc2, 4096, 1024);

  ln_kernel<<<8192, 256, 0, stream>>>(x, ln1_g, ln1_b, xn);

  gemm128<0><<<dim3(3072 / 128, 8192 / 128), 256, 0, stream>>>(
      xn, wt_attn, b_attn, 8192, 3072, 1024,
      nullptr, nullptr, nullptr, qb, kb, vb);

  v_transpose<<<dim3(32, 64), 256, 0, stream>>>(vb, vt);

  attn_kernel<<<dim3(16, 64), 256, 0, stream>>>(qb, kb, vt, ao);

  gemm128<1><<<dim3(1024 / 128, 8192 / 128), 256, 0, stream>>>(
      ao, wt_proj, b_proj, 8192, 1024, 1024,
      x2, nullptr, x, nullptr, nullptr, nullptr);

  ln_kernel<<<8192, 256, 0, stream>>>(x2, ln2_g, ln2_b, xn);

  gemm128<2><<<dim3(4096 / 128, 8192 / 128), 256, 0, stream>>>(
      xn, wt_fc, b_fc, 8192, 4096, 1024,
      nullptr, hm, nullptr, nullptr, nullptr, nullptr);

  gemm128<1><<<dim3(1024 / 128, 8192 / 128), 256, 0, stream>>>(
      hm, wt_fc2, b_fc2, 8192, 1024, 4096,
      out, nullptr, x2, nullptr, nullptr, nullptr);
}

// Round 4
// 477.525 us; speedup vs baseline: 1.2788x; 1.1240x over previous
//
#include <hip/hip_runtime.h>

typedef unsigned short u16;
typedef unsigned int u32;
typedef __attribute__((ext_vector_type(8))) short bf16x8;
typedef __attribute__((ext_vector_type(4))) float f32x4;
typedef __attribute__((ext_vector_type(4))) u32 u32x4;

#define DEV __device__ __forceinline__
#define MFMA16(a, b, c) __builtin_amdgcn_mfma_f32_16x16x32_bf16(a, b, c, 0, 0, 0)

DEV u16 f2bf(float f) {
  u32 u = __float_as_uint(f);
  u32 r = (u + 0x7fffu + ((u >> 16) & 1u)) >> 16;
  return (u16)r;
}

DEV void async16(const void* g, void* l) {
  __builtin_amdgcn_global_load_lds((const __attribute__((address_space(1))) u32*)g,
                                   (__attribute__((address_space(3))) u32*)l, 16, 0, 0);
}

// ---------------- weight transpose+convert: fp32 [K,N] -> bf16 [N,K] ----------------
__global__ __launch_bounds__(256)
void wt_transpose(const float* __restrict__ w, u16* __restrict__ wt, int K, int N) {
  __shared__ float tile[32][33];
  int n0 = blockIdx.x * 32;
  int k0 = blockIdx.y * 32;
  int tx = threadIdx.x;   // 0..31
  int ty = threadIdx.y;   // 0..7
#pragma unroll
  for (int i = 0; i < 4; ++i)
    tile[ty + 8 * i][tx] = w[(size_t)(k0 + ty + 8 * i) * N + n0 + tx];
  __syncthreads();
#pragma unroll
  for (int i = 0; i < 4; ++i) {
    int n = ty + 8 * i;
    wt[(size_t)(n0 + n) * K + k0 + tx] = f2bf(tile[tx][n]);
  }
}

// ---------------- LayerNorm: fp32 row -> bf16 row ----------------
__global__ __launch_bounds__(256)
void ln_kernel(const float* __restrict__ x, const float* __restrict__ g,
               const float* __restrict__ b, u16* __restrict__ out) {
  int row = blockIdx.x;
  int tid = threadIdx.x;
  const float4* xr = (const float4*)(x + (size_t)row * 1024);
  float4 v = xr[tid];
  float s = v.x + v.y + v.z + v.w;
  float ss = v.x * v.x + v.y * v.y + v.z * v.z + v.w * v.w;
#pragma unroll
  for (int o = 32; o > 0; o >>= 1) {
    s += __shfl_down(s, o);
    ss += __shfl_down(ss, o);
  }
  __shared__ float ps[4], pss[4];
  if ((tid & 63) == 0) { ps[tid >> 6] = s; pss[tid >> 6] = ss; }
  __syncthreads();
  s = ps[0] + ps[1] + ps[2] + ps[3];
  ss = pss[0] + pss[1] + pss[2] + pss[3];
  float mu = s * (1.0f / 1024.0f);
  float var = ss * (1.0f / 1024.0f) - mu * mu;
  float rs = rsqrtf(var + 1e-5f);
  float4 gg = ((const float4*)g)[tid];
  float4 bb = ((const float4*)b)[tid];
  ushort4 ov;
  ov.x = f2bf((v.x - mu) * rs * gg.x + bb.x);
  ov.y = f2bf((v.y - mu) * rs * gg.y + bb.y);
  ov.z = f2bf((v.z - mu) * rs * gg.z + bb.z);
  ov.w = f2bf((v.w - mu) * rs * gg.w + bb.w);
  *(ushort4*)(out + (size_t)row * 1024 + tid * 4) = ov;
}

// ---------------- V transpose: bf16 [bh][2048][64] -> [bh][64][2048] ----------------
__global__ __launch_bounds__(256)
void v_transpose(const u16* __restrict__ v, u16* __restrict__ vt) {
  __shared__ u16 t[64][72];
  int s0 = blockIdx.x * 64;
  int bh = blockIdx.y;
  int tid = threadIdx.x;
  const u16* src = v + ((size_t)bh * 2048 + s0) * 64;
#pragma unroll
  for (int p = 0; p < 2; ++p) {
    int r = p * 32 + (tid >> 3);
    int c = (tid & 7) * 8;
    u32x4 a = *(const u32x4*)(src + r * 64 + c);
    const u16* pa = (const u16*)&a;
#pragma unroll
    for (int j = 0; j < 8; ++j) t[r][c + j] = pa[j];
  }
  __syncthreads();
  u16* dst = vt + (size_t)bh * 131072 + s0;
#pragma unroll
  for (int p = 0; p < 2; ++p) {
    int d = p * 32 + (tid >> 3);
    int sc = (tid & 7) * 8;
    u32x4 a;
    u16* pa = (u16*)&a;
#pragma unroll
    for (int j = 0; j < 8; ++j) pa[j] = t[sc + j][d];
    *(u32x4*)(dst + (size_t)d * 2048 + sc) = a;
  }
}

// ---------------- GEMM 128x128 tile, BK=32, 4 waves, m97-style ----------------
// A: bf16 [M,K] row-major. Bt: bf16 [N,K] row-major (i.e. B^T). All dims %128==0, K%32==0.
DEV void stage128x32(const u16* __restrict__ src, long ld, long r0, char* lds, int tid) {
  int wid = tid >> 6;
  const char* g0 = (const char*)(src + r0 * ld);
#pragma unroll
  for (int i = 0; i < 2; ++i) {
    long row = i * 64 + (tid >> 2);
    long cg = tid & 3;
    async16(g0 + (row * ld + cg * 8) * 2, lds + i * 4096 + wid * 1024);
  }
}

template <int EPI>
__global__ __launch_bounds__(256, 2)
void gemm128(const u16* __restrict__ A, const u16* __restrict__ Bt,
             const float* __restrict__ bias, int M, int N, int K,
             float* __restrict__ outf, u16* __restrict__ outb,
             const float* __restrict__ res,
             u16* __restrict__ qp, u16* __restrict__ kp, u16* __restrict__ vp) {
  __shared__ char lds[16384];
  char* ldsA = lds;
  char* ldsB = lds + 8192;
  int tid = threadIdx.x;
  int lane = tid & 63, wid = tid >> 6;
  int wr = wid >> 1, wc = wid & 1;
  long m0 = (long)blockIdx.y * 128;
  long n0 = (long)blockIdx.x * 128;

  f32x4 acc[4][4];
#pragma unroll
  for (int i = 0; i < 4; ++i)
#pragma unroll
    for (int j = 0; j < 4; ++j) acc[i][j] = (f32x4)0.0f;

  int lrow = lane & 15;
  int lkb = (lane >> 4) * 16;  // byte offset of this lane's 8-element k-chunk

  for (int k0 = 0; k0 < K; k0 += 32) {
    stage128x32(A + k0, K, m0, ldsA, tid);
    stage128x32(Bt + k0, K, n0, ldsB, tid);
    __syncthreads();
    bf16x8 af[4], bfr[4];
#pragma unroll
    for (int mi = 0; mi < 4; ++mi)
      af[mi] = *(const bf16x8*)(ldsA + (wr * 64 + mi * 16 + lrow) * 64 + lkb);
#pragma unroll
    for (int ni = 0; ni < 4; ++ni)
      bfr[ni] = *(const bf16x8*)(ldsB + (wc * 64 + ni * 16 + lrow) * 64 + lkb);
#pragma unroll
    for (int mi = 0; mi < 4; ++mi)
#pragma unroll
      for (int ni = 0; ni < 4; ++ni)
        acc[mi][ni] = MFMA16(af[mi], bfr[ni], acc[mi][ni]);
    __syncthreads();
  }

  int rgrp = (lane >> 4) * 4;
#pragma unroll
  for (int mi = 0; mi < 4; ++mi) {
#pragma unroll
    for (int ni = 0; ni < 4; ++ni) {
      long col = n0 + wc * 64 + ni * 16 + (lane & 15);
      float bv = bias[col];
#pragma unroll
      for (int r = 0; r < 4; ++r) {
        long row = m0 + wr * 64 + mi * 16 + rgrp + r;
        float c = acc[mi][ni][r] + bv;
        if (EPI == 0) {
          // QKV scatter: col in [0,3072): part=col>>10, head=(col&1023)>>6, dd=col&63
          int part = (int)(col >> 10);
          int hd = (int)(col & 1023);
          long bq = row >> 11;
          long sq = row & 2047;
          long dst = (((bq << 4) + (hd >> 6)) * 2048 + sq) * 64 + (hd & 63);
          if (part == 0) qp[dst] = f2bf(c * 0.125f);
          else if (part == 1) kp[dst] = f2bf(c);
          else vp[dst] = f2bf(c);
        } else if (EPI == 1) {
          long idx = row * (long)N + col;
          outf[idx] = c + res[idx];
        } else {
          float gl = 0.5f * c * (1.0f + erff(c * 0.70710678118f));
          outb[row * (long)N + col] = f2bf(gl);
        }
      }
    }
  }
}

// ---------------- Flash attention (causal), paired q-tiles for load balance ----------------
// Block j (j=0..7) handles q-tiles {15-j (heavy), j (light)} of 128 rows each against a
// SHARED staged K/V stream (light's tile range is a subset of heavy's). Every block does
// exactly 34 fq-units of MFMA work -> perfect balance. Dbuf staging, XOR-swizzled LDS.
__global__ __launch_bounds__(256, 2)
void attn_kernel(const u16* __restrict__ q, const u16* __restrict__ k,
                 const u16* __restrict__ vt, u16* __restrict__ outp) {
  __shared__ char ldsK[2][8192];   // [64 kv][64 d] bf16, swizzled, double-buffered
  __shared__ char ldsV[2][8192];   // [64 d][64 kv] bf16 (V^T tile), swizzled, dbuf
  __shared__ char ldsP[4][4096];   // per-wave P [32][64] bf16, swizzled
  int j = blockIdx.x;              // 0..7
  int bh = blockIdx.y;
  int tid = threadIdx.x, lane = tid & 63, w = tid >> 6;
  const u16* qb = q + (size_t)bh * 131072;
  const u16* kb = k + (size_t)bh * 131072;
  const u16* vb = vt + (size_t)bh * 131072;

  int lr = lane & 15, lg = lane >> 4;
  int swz = (lr & 7) << 4;  // read-side XOR (row & 7 == lr & 7 for all fragment rows)

  const int qih = 15 - j, qil = j;
  const int NTH = 2 * qih + 2;  // heavy tile count (>= 18)
  const int NTL = 2 * qil + 2;  // light tile count (<= 16)

  bf16x8 qf[2][2][2];
#pragma unroll
  for (int p = 0; p < 2; ++p) {
    int q0p = (p ? qil : qih) * 128;
#pragma unroll
    for (int fq = 0; fq < 2; ++fq) {
      const u16* qr = qb + (size_t)(q0p + w * 32 + fq * 16 + lr) * 64 + lg * 8;
      qf[p][fq][0] = *(const bf16x8*)(qr);
      qf[p][fq][1] = *(const bf16x8*)(qr + 32);
    }
  }

  f32x4 o[2][2][4];
  float m_run[2][2][4], l_run[2][2][4];
#pragma unroll
  for (int p = 0; p < 2; ++p)
#pragma unroll
    for (int fq = 0; fq < 2; ++fq)
#pragma unroll
      for (int i = 0; i < 4; ++i) {
        o[p][fq][i] = (f32x4)0.0f;
        m_run[p][fq][i] = -1e30f;
        l_run[p][fq][i] = 0.0f;
      }

  auto stage = [&](int buf, int t) {
    int kv0 = t * 64;
    const char* gk = (const char*)(kb + (size_t)kv0 * 64);
#pragma unroll
    for (int i = 0; i < 2; ++i) {
      int off = i * 4096 + tid * 16;
      int src = off ^ (((off >> 7) & 7) << 4);
      async16(gk + src, &ldsK[buf][i * 4096 + w * 1024]);
    }
#pragma unroll
    for (int i = 0; i < 2; ++i) {
      int vrow = i * 32 + (tid >> 3);
      int cb = ((tid & 7) * 16) ^ ((vrow & 7) << 4);
      async16((const char*)vb + (size_t)vrow * 4096 + (size_t)kv0 * 2 + cb,
              &ldsV[buf][i * 4096 + w * 1024]);
    }
  };

  stage(0, 0);
  __syncthreads();  // drain prologue loads
  int cur = 0;

  for (int t = 0; t < NTH; ++t) {
    if (t + 1 < NTH) stage(cur ^ 1, t + 1);  // issue next-tile loads EARLY
    int kv0 = t * 64;

#pragma unroll
    for (int p = 0; p < 2; ++p) {
      if (p == 1 && t >= NTL) break;  // light q-tile only needs its causal range
      int q0p = (p ? qil : qih) * 128;
      int ntp = p ? NTL : NTH;

      // S = Q K^T  (Q pre-scaled by 1/sqrt(d))
      f32x4 s[2][4];
      __builtin_amdgcn_s_setprio(1);
#pragma unroll
      for (int nf = 0; nf < 4; ++nf) {
#pragma unroll
        for (int fq = 0; fq < 2; ++fq) s[fq][nf] = (f32x4)0.0f;
#pragma unroll
        for (int ks = 0; ks < 2; ++ks) {
          bf16x8 kf = *(const bf16x8*)(&ldsK[cur][(nf * 16 + lr) * 128 +
                                                 ((ks * 64 + lg * 16) ^ swz)]);
#pragma unroll
          for (int fq = 0; fq < 2; ++fq)
            s[fq][nf] = MFMA16(qf[p][fq][ks], kf, s[fq][nf]);
        }
      }
      __builtin_amdgcn_s_setprio(0);

      // causal mask — only the last two tiles of this q-tile touch the diagonal
      if (t + 2 >= ntp) {
#pragma unroll
        for (int fq = 0; fq < 2; ++fq)
#pragma unroll
          for (int nf = 0; nf < 4; ++nf)
#pragma unroll
            for (int r = 0; r < 4; ++r) {
              int qrow = q0p + w * 32 + fq * 16 + lg * 4 + r;
              int kvc = kv0 + nf * 16 + lr;
              if (kvc > qrow) s[fq][nf][r] = -1e30f;
            }
      }

      // online softmax
      float mnew[2][4], alpha[2][4], psum[2][4];
#pragma unroll
      for (int fq = 0; fq < 2; ++fq)
#pragma unroll
        for (int r = 0; r < 4; ++r) {
          float pm = fmaxf(fmaxf(s[fq][0][r], s[fq][1][r]),
                           fmaxf(s[fq][2][r], s[fq][3][r]));
#pragma unroll
          for (int m = 1; m < 16; m <<= 1) pm = fmaxf(pm, __shfl_xor(pm, m));
          mnew[fq][r] = fmaxf(m_run[p][fq][r], pm);
          alpha[fq][r] = __expf(m_run[p][fq][r] - mnew[fq][r]);
          m_run[p][fq][r] = mnew[fq][r];
          psum[fq][r] = 0.0f;
        }
#pragma unroll
      for (int fq = 0; fq < 2; ++fq)
#pragma unroll
        for (int nf = 0; nf < 4; ++nf)
#pragma unroll
          for (int r = 0; r < 4; ++r) {
            float pv = __expf(s[fq][nf][r] - mnew[fq][r]);
            psum[fq][r] += pv;
            int prow = fq * 16 + lg * 4 + r;
            int pb = ((nf * 16 + lr) * 2) ^ ((prow & 7) << 4);
            *(u16*)(&ldsP[w][prow * 128 + pb]) = f2bf(pv);
          }
#pragma unroll
      for (int fq = 0; fq < 2; ++fq)
#pragma unroll
        for (int r = 0; r < 4; ++r) {
          float ps2 = psum[fq][r];
#pragma unroll
          for (int m = 1; m < 16; m <<= 1) ps2 += __shfl_xor(ps2, m);
          l_run[p][fq][r] = l_run[p][fq][r] * alpha[fq][r] + ps2;
        }
#pragma unroll
      for (int fq = 0; fq < 2; ++fq)
#pragma unroll
        for (int nf = 0; nf < 4; ++nf)
#pragma unroll
          for (int r = 0; r < 4; ++r) o[p][fq][nf][r] *= alpha[fq][r];

      // O += P V   (P per-wave in LDS; wave-local DS ops are in-order)
      __builtin_amdgcn_s_setprio(1);
#pragma unroll
      for (int ks = 0; ks < 2; ++ks) {
        bf16x8 pf[2];
#pragma unroll
        for (int fq = 0; fq < 2; ++fq)
          pf[fq] = *(const bf16x8*)(&ldsP[w][(fq * 16 + lr) * 128 +
                                             ((ks * 64 + lg * 16) ^ swz)]);
#pragma unroll
        for (int nf = 0; nf < 4; ++nf) {
          bf16x8 vf = *(const bf16x8*)(&ldsV[cur][(nf * 16 + lr) * 128 +
                                                 ((ks * 64 + lg * 16) ^ swz)]);
#pragma unroll
          for (int fq = 0; fq < 2; ++fq)
            o[p][fq][nf] = MFMA16(pf[fq], vf, o[p][fq][nf]);
        }
      }
      __builtin_amdgcn_s_setprio(0);
    }

    __syncthreads();  // drains prefetch vmcnt + syncs buffer swap
    cur ^= 1;
  }

  int b = bh >> 4, h = bh & 15;
#pragma unroll
  for (int p = 0; p < 2; ++p) {
    int q0p = (p ? qil : qih) * 128;
#pragma unroll
    for (int fq = 0; fq < 2; ++fq)
#pragma unroll
      for (int r = 0; r < 4; ++r) {
        int qrow = q0p + w * 32 + fq * 16 + lg * 4 + r;
        float inv = 1.0f / l_run[p][fq][r];
        size_t base = ((size_t)(b * 2048 + qrow)) * 1024 + h * 64;
#pragma unroll
        for (int nf = 0; nf < 4; ++nf)
          outp[base + nf * 16 + lr] = f2bf(o[p][fq][nf][r] * inv);
      }
  }
}

// ---------------- launch ----------------
extern "C" void kernel_launch(void* const* d_in, const int* in_sizes, int n_in,
                              void* d_out, int out_size, void* d_ws, size_t ws_size,
                              hipStream_t stream) {
  const float* x      = (const float*)d_in[0];
  const float* ln1_g  = (const float*)d_in[1];
  const float* ln1_b  = (const float*)d_in[2];
  const float* w_attn = (const float*)d_in[3];
  const float* b_attn = (const float*)d_in[4];
  const float* w_proj = (const float*)d_in[5];
  const float* b_proj = (const float*)d_in[6];
  const float* ln2_g  = (const float*)d_in[7];
  const float* ln2_b  = (const float*)d_in[8];
  const float* w_fc   = (const float*)d_in[9];
  const float* b_fc   = (const float*)d_in[10];
  const float* w_fc2  = (const float*)d_in[11];
  const float* b_fc2  = (const float*)d_in[12];
  float* out = (float*)d_out;

  char* ws = (char*)d_ws;
  u16* wt_attn = (u16*)(ws + 0);          //  6291456 B
  u16* wt_proj = (u16*)(ws + 6291456);    //  2097152 B
  u16* wt_fc   = (u16*)(ws + 8388608);    //  8388608 B
  u16* wt_fc2  = (u16*)(ws + 16777216);   //  8388608 B
  u16* xn      = (u16*)(ws + 25165824);   // 16777216 B (LN1 out, reused for LN2 out)
  float* x2    = (float*)(ws + 41943040); // 33554432 B
  char* region = ws + 75497472;           // 83886080 B union region
  u16* qb = (u16*)(region);               // 16 MiB each
  u16* kb = (u16*)(region + 16777216);
  u16* vb = (u16*)(region + 33554432);
  u16* vt = (u16*)(region + 50331648);
  u16* ao = (u16*)(region + 67108864);
  u16* hm = (u16*)(region);               // 64 MiB, overlaps dead q/k/v/vt

  dim3 tb(32, 8);
  wt_transpose<<<dim3(3072 / 32, 1024 / 32), tb, 0, stream>>>(w_attn, wt_attn, 1024, 3072);
  wt_transpose<<<dim3(1024 / 32, 1024 / 32), tb, 0, stream>>>(w_proj, wt_proj, 1024, 1024);
  wt_transpose<<<dim3(4096 / 32, 1024 / 32), tb, 0, stream>>>(w_fc, wt_fc, 1024, 4096);
  wt_transpose<<<dim3(1024 / 32, 4096 / 32), tb, 0, stream>>>(w_fc2, wt_fc2, 4096, 1024);

  ln_kernel<<<8192, 256, 0, stream>>>(x, ln1_g, ln1_b, xn);

  gemm128<0><<<dim3(3072 / 128, 8192 / 128), 256, 0, stream>>>(
      xn, wt_attn, b_attn, 8192, 3072, 1024,
      nullptr, nullptr, nullptr, qb, kb, vb);

  v_transpose<<<dim3(32, 64), 256, 0, stream>>>(vb, vt);

  attn_kernel<<<dim3(8, 64), 256, 0, stream>>>(qb, kb, vt, ao);

  gemm128<1><<<dim3(1024 / 128, 8192 / 128), 256, 0, stream>>>(
      ao, wt_proj, b_proj, 8192, 1024, 1024,
      x2, nullptr, x, nullptr, nullptr, nullptr);

  ln_kernel<<<8192, 256, 0, stream>>>(x2, ln2_g, ln2_b, xn);

  gemm128<2><<<dim3(4096 / 128, 8192 / 128), 256, 0, stream>>>(
      xn, wt_fc, b_fc, 8192, 4096, 1024,
      nullptr, hm, nullptr, nullptr, nullptr, nullptr);

  gemm128<1><<<dim3(1024 / 128, 8192 / 128), 256, 0, stream>>>(
      hm, wt_fc2, b_fc2, 8192, 1024, 4096,
      out, nullptr, x2, nullptr, nullptr, nullptr);
}